// Round 1
// baseline (6722.001 us; speedup 1.0000x reference)
//
#include <hip/hip_runtime.h>
#include <math.h>

#define NEG_SLOPE 0.2f

__device__ __forceinline__ void atomicMaxFloat(float* addr, float val) {
    // int/uint trick: correct for all finite floats and -inf init
    if (val >= 0.0f) atomicMax((int*)addr, __float_as_int(val));
    else             atomicMin((unsigned int*)addr, __float_as_uint(val));
}

// --- init kernels -----------------------------------------------------------
__global__ void init_layer(float* __restrict__ M, float* __restrict__ DEN,
                           float* __restrict__ AGG, long nm, long nagg) {
    long stride = (long)gridDim.x * blockDim.x;
    long t0 = (long)blockIdx.x * blockDim.x + threadIdx.x;
    for (long t = t0; t < nm; t += stride) { M[t] = -INFINITY; DEN[t] = 0.0f; }
    for (long t = t0; t < nagg; t += stride) AGG[t] = 0.0f;
}

// --- fused GEMM (OC=64) + attention-alpha epilogue --------------------------
// C[n][c] = sum_k A[n][k] * W[k*64+c];  alpha_s[n][h] = sum_ch C[n][h][ch]*a_src[h][ch]
template<int K, int CH>   // CH = channels per head (8 or 64); H = 64/CH
__global__ void gemm_alpha(const float* __restrict__ A, const float* __restrict__ W,
                           const float* __restrict__ a_src, const float* __restrict__ a_dst,
                           float* __restrict__ Hout, float* __restrict__ AS,
                           float* __restrict__ AD, int N) {
    __shared__ float Wl[K * 64];
    __shared__ float Ar[4][K];
    const int tid = threadIdx.x;
    for (int i = tid; i < K * 64; i += 256) Wl[i] = W[i];
    const int g = tid >> 6;       // wave id within block (4 nodes in flight)
    const int c = tid & 63;       // output column = lane
    const int H = 64 / CH;
    __syncthreads();
    for (int base = blockIdx.x * 4; base < N; base += gridDim.x * 4) {
        int n = base + g;
        if (n < N) {
            for (int k = c; k < K; k += 64) Ar[g][k] = A[(size_t)n * K + k];
        }
        __syncthreads();
        if (n < N) {
            float acc = 0.0f;
            #pragma unroll 8
            for (int k = 0; k < K; ++k) acc = fmaf(Ar[g][k], Wl[k * 64 + c], acc);
            Hout[(size_t)n * 64 + c] = acc;
            float vs = acc * a_src[c];
            float vd = acc * a_dst[c];
            #pragma unroll
            for (int off = 1; off < CH; off <<= 1) {
                vs += __shfl_xor(vs, off, 64);
                vd += __shfl_xor(vd, off, 64);
            }
            if ((c & (CH - 1)) == 0) {
                int h = c / CH;
                AS[(size_t)n * H + h] = vs;
                AD[(size_t)n * H + h] = vd;
            }
        }
        __syncthreads();
    }
}

// --- edge pass 1: segment max ----------------------------------------------
template<int H>
__global__ void edge_max(const int* __restrict__ ei, int E, int N,
                         const float* __restrict__ AS, const float* __restrict__ AD,
                         float* __restrict__ M) {
    int total = (E + N) * H;
    int stride = gridDim.x * blockDim.x;
    for (int t = blockIdx.x * blockDim.x + threadIdx.x; t < total; t += stride) {
        int h = t % H;
        int eid = t / H;
        int s, d;
        if (eid < E) { s = ei[eid]; d = ei[E + eid]; }
        else         { s = d = eid - E; }
        float e = AS[(size_t)s * H + h] + AD[(size_t)d * H + h];
        e = e > 0.0f ? e : NEG_SLOPE * e;
        atomicMaxFloat(&M[(size_t)d * H + h], e);
    }
}

// --- edge pass 2: fused exp + denom-sum + weighted scatter-add --------------
template<int H, int CPT>  // CH=64/H channels/head, CPT channels handled per thread
__global__ void edge_agg(const int* __restrict__ ei, int E, int N,
                         const float* __restrict__ AS, const float* __restrict__ AD,
                         const float* __restrict__ M, const float* __restrict__ Hin,
                         float* __restrict__ DEN, float* __restrict__ AGG) {
    const int CH = 64 / H;
    const int NCH = CH / CPT;      // chunks per head
    int total = (E + N) * H * NCH;
    int stride = gridDim.x * blockDim.x;
    for (int t = blockIdx.x * blockDim.x + threadIdx.x; t < total; t += stride) {
        int chunk = t % NCH;
        int r = t / NCH;
        int h = r % H;
        int eid = r / H;
        int s, d;
        if (eid < E) { s = ei[eid]; d = ei[E + eid]; }
        else         { s = d = eid - E; }
        float e = AS[(size_t)s * H + h] + AD[(size_t)d * H + h];
        e = e > 0.0f ? e : NEG_SLOPE * e;
        float p = __expf(e - M[(size_t)d * H + h]);
        if (chunk == 0) atomicAdd(&DEN[(size_t)d * H + h], p);
        int cbase = h * CH + chunk * CPT;
        const float* hv = Hin + (size_t)s * 64 + cbase;
        float* ag = AGG + (size_t)d * 64 + cbase;
        #pragma unroll
        for (int i = 0; i < CPT; ++i) atomicAdd(&ag[i], p * hv[i]);
    }
}

// --- layer-1 epilogue: normalize + bias + ELU (in place ok) -----------------
__global__ void normalize_elu(const float* __restrict__ AGG, const float* __restrict__ DEN,
                              const float* __restrict__ b, float* __restrict__ OUT, int N) {
    long total = (long)N * 64;
    long stride = (long)gridDim.x * blockDim.x;
    for (long t = (long)blockIdx.x * blockDim.x + threadIdx.x; t < total; t += stride) {
        int c = (int)(t & 63);
        long n = t >> 6;
        float v = AGG[t] / (DEN[n * 8 + (c >> 3)] + 1e-16f) + b[c];
        OUT[t] = v > 0.0f ? v : expf(v) - 1.0f;
    }
}

// --- final: normalize + bias + log_softmax (one wave per node) --------------
__global__ void finalize(const float* __restrict__ AGG, const float* __restrict__ DEN,
                         const float* __restrict__ b, float* __restrict__ OUT, int N) {
    int lane = threadIdx.x & 63;
    int wid = blockIdx.x * (blockDim.x >> 6) + (threadIdx.x >> 6);
    int nw = gridDim.x * (blockDim.x >> 6);
    for (int n = wid; n < N; n += nw) {
        float v = AGG[(size_t)n * 64 + lane] / (DEN[n] + 1e-16f) + b[lane];
        float m = v;
        #pragma unroll
        for (int off = 32; off; off >>= 1) m = fmaxf(m, __shfl_xor(m, off, 64));
        float s = expf(v - m);
        #pragma unroll
        for (int off = 32; off; off >>= 1) s += __shfl_xor(s, off, 64);
        OUT[(size_t)n * 64 + lane] = v - m - logf(s);
    }
}

extern "C" void kernel_launch(void* const* d_in, const int* in_sizes, int n_in,
                              void* d_out, int out_size, void* d_ws, size_t ws_size,
                              hipStream_t stream) {
    const float* x    = (const float*)d_in[0];
    const int*   ei   = (const int*)d_in[1];
    const float* W1   = (const float*)d_in[2];
    const float* as1w = (const float*)d_in[3];
    const float* ad1w = (const float*)d_in[4];
    const float* b1   = (const float*)d_in[5];
    const float* W2   = (const float*)d_in[6];
    const float* as2w = (const float*)d_in[7];
    const float* ad2w = (const float*)d_in[8];
    const float* b2   = (const float*)d_in[9];
    const int N = in_sizes[0] / 128;   // 100000
    const int E = in_sizes[1] / 2;     // 1600000

    float* ws = (float*)d_ws;
    size_t N64 = (size_t)N * 64, N8 = (size_t)N * 8;
    float* h1   = ws;             // N*64
    float* AS1  = h1 + N64;       // N*8
    float* AD1  = AS1 + N8;       // N*8
    float* M1   = AD1 + N8;       // N*8
    float* DEN1 = M1 + N8;        // N*8
    float* AGG1 = DEN1 + N8;      // N*64 (becomes elu(h) in place)
    float* h2   = AGG1 + N64;     // N*64
    float* AS2  = h2 + N64;       // N
    float* AD2  = AS2 + N;        // N
    float* M2   = AD2 + N;        // N
    float* DEN2 = M2 + N;         // N
    float* AGG2 = h1;             // reuse h1 (dead after layer-1 agg)

    // ---- layer 1 ----
    init_layer<<<2048, 256, 0, stream>>>(M1, DEN1, AGG1, (long)N8, (long)N64);
    gemm_alpha<128, 8><<<1024, 256, 0, stream>>>(x, W1, as1w, ad1w, h1, AS1, AD1, N);
    edge_max<8><<<8192, 256, 0, stream>>>(ei, E, N, AS1, AD1, M1);
    edge_agg<8, 8><<<8192, 256, 0, stream>>>(ei, E, N, AS1, AD1, M1, h1, DEN1, AGG1);
    normalize_elu<<<4096, 256, 0, stream>>>(AGG1, DEN1, b1, AGG1, N);

    // ---- layer 2 ----
    init_layer<<<2048, 256, 0, stream>>>(M2, DEN2, AGG2, (long)N, (long)N64);
    gemm_alpha<64, 64><<<1024, 256, 0, stream>>>(AGG1, W2, as2w, ad2w, h2, AS2, AD2, N);
    edge_max<1><<<4096, 256, 0, stream>>>(ei, E, N, AS2, AD2, M2);
    edge_agg<1, 8><<<8192, 256, 0, stream>>>(ei, E, N, AS2, AD2, M2, h2, DEN2, AGG2);
    finalize<<<2048, 256, 0, stream>>>(AGG2, DEN2, b2, (float*)d_out, N);
}

// Round 2
// 867.516 us; speedup vs baseline: 7.7486x; 7.7486x over previous
//
#include <hip/hip_runtime.h>
#include <math.h>

#define NEG_SLOPE 0.2f
#define SCAN_CHUNK 1024

// ---------------------------------------------------------------------------
// CSR build: histogram -> hierarchical exclusive scan -> bump scatter
// ---------------------------------------------------------------------------
__global__ void histogram(const int* __restrict__ ei, int E, int N, int* __restrict__ cnt) {
    int stride = gridDim.x * blockDim.x;
    int total = E + N;
    for (int t = blockIdx.x * blockDim.x + threadIdx.x; t < total; t += stride) {
        int d = (t < E) ? ei[E + t] : (t - E);   // self-loops appended
        atomicAdd(&cnt[d], 1);
    }
}

__global__ void scan_part(const int* __restrict__ cnt, int n, int* __restrict__ part) {
    __shared__ int sdata[256];
    int b = blockIdx.x, tid = threadIdx.x;
    int base = b * SCAN_CHUNK;
    int sum = 0;
    for (int i = tid; i < SCAN_CHUNK; i += 256) {
        int idx = base + i;
        sum += (idx < n) ? cnt[idx] : 0;
    }
    sdata[tid] = sum; __syncthreads();
    for (int s = 128; s > 0; s >>= 1) {
        if (tid < s) sdata[tid] += sdata[tid + s];
        __syncthreads();
    }
    if (tid == 0) part[b] = sdata[0];
}

// exclusive scan of <=128 partials, one wave
__global__ void scan_tops(int* __restrict__ part, int nb) {
    int lane = threadIdx.x;
    int v0 = (lane < nb) ? part[lane] : 0;
    int i1 = lane + 64;
    int v1 = (i1 < nb) ? part[i1] : 0;
    int o0 = v0, o1 = v1;
    for (int off = 1; off < 64; off <<= 1) {
        int t = __shfl_up(v0, off, 64); if (lane >= off) v0 += t;
        t = __shfl_up(v1, off, 64);     if (lane >= off) v1 += t;
    }
    int tot0 = __shfl(v0, 63, 64);
    if (lane < nb) part[lane] = v0 - o0;
    if (i1 < nb)   part[i1]   = v1 - o1 + tot0;
}

__global__ void scan_final(const int* __restrict__ cnt, int n, int total,
                           const int* __restrict__ part,
                           int* __restrict__ row_ptr, int* __restrict__ cursor) {
    __shared__ int sdata[256];
    int b = blockIdx.x, tid = threadIdx.x;
    int base = b * SCAN_CHUNK + tid * 4;
    int v[4]; int s = 0;
    #pragma unroll
    for (int j = 0; j < 4; ++j) {
        int idx = base + j;
        v[j] = (idx < n) ? cnt[idx] : 0;
        s += v[j];
    }
    sdata[tid] = s; __syncthreads();
    for (int off = 1; off < 256; off <<= 1) {
        int t = (tid >= off) ? sdata[tid - off] : 0;
        __syncthreads();
        sdata[tid] += t;
        __syncthreads();
    }
    int run = part[b] + sdata[tid] - s;   // global exclusive base for this thread
    #pragma unroll
    for (int j = 0; j < 4; ++j) {
        int idx = base + j;
        if (idx < n) { row_ptr[idx] = run; cursor[idx] = run; }
        run += v[j];
    }
    if (b == 0 && tid == 0) row_ptr[n] = total;
}

__global__ void scatter_edges(const int* __restrict__ ei, int E, int N,
                              int* __restrict__ cursor, int* __restrict__ col) {
    int stride = gridDim.x * blockDim.x;
    int total = E + N;
    for (int t = blockIdx.x * blockDim.x + threadIdx.x; t < total; t += stride) {
        int s, d;
        if (t < E) { s = ei[t]; d = ei[E + t]; }
        else       { s = d = t - E; }
        int pos = atomicAdd(&cursor[d], 1);
        col[pos] = s;
    }
}

// ---------------------------------------------------------------------------
// fused GEMM (OC=64) + attention-alpha epilogue (unchanged from round 1)
// ---------------------------------------------------------------------------
template<int K, int CH>   // CH = channels per head; H = 64/CH
__global__ void gemm_alpha(const float* __restrict__ A, const float* __restrict__ W,
                           const float* __restrict__ a_src, const float* __restrict__ a_dst,
                           float* __restrict__ Hout, float* __restrict__ AS,
                           float* __restrict__ AD, int N) {
    __shared__ float Wl[K * 64];
    __shared__ float Ar[4][K];
    const int tid = threadIdx.x;
    for (int i = tid; i < K * 64; i += 256) Wl[i] = W[i];
    const int g = tid >> 6;
    const int c = tid & 63;
    const int H = 64 / CH;
    __syncthreads();
    for (int base = blockIdx.x * 4; base < N; base += gridDim.x * 4) {
        int n = base + g;
        if (n < N) {
            for (int k = c; k < K; k += 64) Ar[g][k] = A[(size_t)n * K + k];
        }
        __syncthreads();
        if (n < N) {
            float acc = 0.0f;
            #pragma unroll 8
            for (int k = 0; k < K; ++k) acc = fmaf(Ar[g][k], Wl[k * 64 + c], acc);
            Hout[(size_t)n * 64 + c] = acc;
            float vs = acc * a_src[c];
            float vd = acc * a_dst[c];
            #pragma unroll
            for (int off = 1; off < CH; off <<= 1) {
                vs += __shfl_xor(vs, off, 64);
                vd += __shfl_xor(vd, off, 64);
            }
            if ((c & (CH - 1)) == 0) {
                int h = c / CH;
                AS[(size_t)n * H + h] = vs;
                AD[(size_t)n * H + h] = vd;
            }
        }
        __syncthreads();
    }
}

// ---------------------------------------------------------------------------
// CSR gather aggregation: one wave per dst node, 64 lanes = 64 channels.
// Two passes (segment max, then exp/sum/accumulate), fused epilogue.
// ---------------------------------------------------------------------------
template<int H, bool FINAL>
__global__ void aggregate(const int* __restrict__ row_ptr, const int* __restrict__ col,
                          const float* __restrict__ AS, const float* __restrict__ AD,
                          const float* __restrict__ Hin, const float* __restrict__ bias,
                          float* __restrict__ OUT, int N) {
    const int CH = 64 / H;
    int lane = threadIdx.x & 63;
    int wid = (blockIdx.x * blockDim.x + threadIdx.x) >> 6;
    int nw = (gridDim.x * blockDim.x) >> 6;
    int h = lane / CH;
    for (int n = wid; n < N; n += nw) {
        int beg = row_ptr[n], end = row_ptr[n + 1];
        float ad = AD[(size_t)n * H + h];
        // pass 1: segment max
        float m = -INFINITY;
        for (int base = beg; base < end; base += 64) {
            int cnt = min(64, end - base);
            int myc = (lane < cnt) ? col[base + lane] : 0;
            for (int j = 0; j < cnt; ++j) {
                int s = __shfl(myc, j, 64);
                float e = AS[(size_t)s * H + h] + ad;
                e = e > 0.0f ? e : NEG_SLOPE * e;
                m = fmaxf(m, e);
            }
        }
        // pass 2: exp-sum + weighted gather-accumulate
        float den = 0.0f, acc = 0.0f;
        for (int base = beg; base < end; base += 64) {
            int cnt = min(64, end - base);
            int myc = (lane < cnt) ? col[base + lane] : 0;
            for (int j = 0; j < cnt; ++j) {
                int s = __shfl(myc, j, 64);
                float e = AS[(size_t)s * H + h] + ad;
                e = e > 0.0f ? e : NEG_SLOPE * e;
                float p = __expf(e - m);
                den += p;
                acc = fmaf(p, Hin[(size_t)s * 64 + lane], acc);
            }
        }
        float v = acc / (den + 1e-16f) + bias[lane];
        if (!FINAL) {
            v = v > 0.0f ? v : expf(v) - 1.0f;   // ELU
            OUT[(size_t)n * 64 + lane] = v;
        } else {
            float mm = v;
            #pragma unroll
            for (int off = 32; off; off >>= 1) mm = fmaxf(mm, __shfl_xor(mm, off, 64));
            float ss = __expf(v - mm);
            #pragma unroll
            for (int off = 32; off; off >>= 1) ss += __shfl_xor(ss, off, 64);
            OUT[(size_t)n * 64 + lane] = v - mm - logf(ss);
        }
    }
}

// ---------------------------------------------------------------------------
extern "C" void kernel_launch(void* const* d_in, const int* in_sizes, int n_in,
                              void* d_out, int out_size, void* d_ws, size_t ws_size,
                              hipStream_t stream) {
    const float* x    = (const float*)d_in[0];
    const int*   ei   = (const int*)d_in[1];
    const float* W1   = (const float*)d_in[2];
    const float* as1w = (const float*)d_in[3];
    const float* ad1w = (const float*)d_in[4];
    const float* b1   = (const float*)d_in[5];
    const float* W2   = (const float*)d_in[6];
    const float* as2w = (const float*)d_in[7];
    const float* ad2w = (const float*)d_in[8];
    const float* b2   = (const float*)d_in[9];
    const int N = in_sizes[0] / 128;   // 100000
    const int E = in_sizes[1] / 2;     // 1600000
    const int total = E + N;
    const int NB = (N + SCAN_CHUNK - 1) / SCAN_CHUNK;   // 98

    float* ws = (float*)d_ws;
    size_t N64 = (size_t)N * 64, N8 = (size_t)N * 8;
    size_t off = 0;
    float* h1   = ws + off; off += N64;
    float* AGG1 = ws + off; off += N64;   // elu(layer-1 out), input to layer-2 gemm
    float* h2   = ws + off; off += N64;
    float* AS1  = ws + off; off += N8;
    float* AD1  = ws + off; off += N8;
    float* AS2  = ws + off; off += N;
    float* AD2  = ws + off; off += N;
    int* row_ptr = (int*)(ws + off);      // N+1
    int* cursor  = row_ptr + (N + 1);     // N (also degree counts)
    int* col     = cursor + N;            // E+N
    int* part    = col + total;           // 128

    // ---- CSR build (graph shared by both layers) ----
    hipMemsetAsync(cursor, 0, (size_t)N * sizeof(int), stream);
    histogram<<<4096, 256, 0, stream>>>(ei, E, N, cursor);
    scan_part<<<NB, 256, 0, stream>>>(cursor, N, part);
    scan_tops<<<1, 64, 0, stream>>>(part, NB);
    scan_final<<<NB, 256, 0, stream>>>(cursor, N, total, part, row_ptr, cursor);
    scatter_edges<<<4096, 256, 0, stream>>>(ei, E, N, cursor, col);

    // ---- layer 1 ----
    gemm_alpha<128, 8><<<1024, 256, 0, stream>>>(x, W1, as1w, ad1w, h1, AS1, AD1, N);
    aggregate<8, false><<<(N + 3) / 4, 256, 0, stream>>>(row_ptr, col, AS1, AD1, h1, b1, AGG1, N);

    // ---- layer 2 ----
    gemm_alpha<64, 64><<<1024, 256, 0, stream>>>(AGG1, W2, as2w, ad2w, h2, AS2, AD2, N);
    aggregate<1, true><<<(N + 3) / 4, 256, 0, stream>>>(row_ptr, col, AS2, AD2, h2, b2, (float*)d_out, N);
}

// Round 3
// 474.798 us; speedup vs baseline: 14.1576x; 1.8271x over previous
//
#include <hip/hip_runtime.h>
#include <math.h>

#define NEG_SLOPE 0.2f
#define SCAN_CHUNK 1024

// ---------------- bf16 helpers ----------------
__device__ __forceinline__ unsigned short f2bf(float f) {
    unsigned int u = __float_as_uint(f);
    unsigned int r = (u + 0x7FFFu + ((u >> 16) & 1u)) >> 16;   // round-to-nearest-even
    return (unsigned short)r;
}
__device__ __forceinline__ float bfl(unsigned int u) { return __uint_as_float(u << 16); }
__device__ __forceinline__ float bfh(unsigned int u) { return __uint_as_float(u & 0xffff0000u); }

// ---------------------------------------------------------------------------
// CSR build: histogram -> hierarchical exclusive scan -> bump scatter
// ---------------------------------------------------------------------------
__global__ void histogram(const int* __restrict__ ei, int E, int N, int* __restrict__ cnt) {
    int stride = gridDim.x * blockDim.x;
    int total = E + N;
    for (int t = blockIdx.x * blockDim.x + threadIdx.x; t < total; t += stride) {
        int d = (t < E) ? ei[E + t] : (t - E);
        atomicAdd(&cnt[d], 1);
    }
}

__global__ void scan_part(const int* __restrict__ cnt, int n, int* __restrict__ part) {
    __shared__ int sdata[256];
    int b = blockIdx.x, tid = threadIdx.x;
    int base = b * SCAN_CHUNK;
    int sum = 0;
    for (int i = tid; i < SCAN_CHUNK; i += 256) {
        int idx = base + i;
        sum += (idx < n) ? cnt[idx] : 0;
    }
    sdata[tid] = sum; __syncthreads();
    for (int s = 128; s > 0; s >>= 1) {
        if (tid < s) sdata[tid] += sdata[tid + s];
        __syncthreads();
    }
    if (tid == 0) part[b] = sdata[0];
}

__global__ void scan_tops(int* __restrict__ part, int nb) {
    int lane = threadIdx.x;
    int v0 = (lane < nb) ? part[lane] : 0;
    int i1 = lane + 64;
    int v1 = (i1 < nb) ? part[i1] : 0;
    int o0 = v0, o1 = v1;
    for (int off = 1; off < 64; off <<= 1) {
        int t = __shfl_up(v0, off, 64); if (lane >= off) v0 += t;
        t = __shfl_up(v1, off, 64);     if (lane >= off) v1 += t;
    }
    int tot0 = __shfl(v0, 63, 64);
    if (lane < nb) part[lane] = v0 - o0;
    if (i1 < nb)   part[i1]   = v1 - o1 + tot0;
}

__global__ void scan_final(const int* __restrict__ cnt, int n, int total,
                           const int* __restrict__ part,
                           int* __restrict__ row_ptr, int* __restrict__ cursor) {
    __shared__ int sdata[256];
    int b = blockIdx.x, tid = threadIdx.x;
    int base = b * SCAN_CHUNK + tid * 4;
    int v[4]; int s = 0;
    #pragma unroll
    for (int j = 0; j < 4; ++j) {
        int idx = base + j;
        v[j] = (idx < n) ? cnt[idx] : 0;
        s += v[j];
    }
    sdata[tid] = s; __syncthreads();
    for (int off = 1; off < 256; off <<= 1) {
        int t = (tid >= off) ? sdata[tid - off] : 0;
        __syncthreads();
        sdata[tid] += t;
        __syncthreads();
    }
    int run = part[b] + sdata[tid] - s;
    #pragma unroll
    for (int j = 0; j < 4; ++j) {
        int idx = base + j;
        if (idx < n) { row_ptr[idx] = run; cursor[idx] = run; }
        run += v[j];
    }
    if (b == 0 && tid == 0) row_ptr[n] = total;
}

__global__ void scatter_edges(const int* __restrict__ ei, int E, int N,
                              int* __restrict__ cursor, int* __restrict__ col) {
    int stride = gridDim.x * blockDim.x;
    int total = E + N;
    for (int t = blockIdx.x * blockDim.x + threadIdx.x; t < total; t += stride) {
        int s, d;
        if (t < E) { s = ei[t]; d = ei[E + t]; }
        else       { s = d = t - E; }
        int pos = atomicAdd(&cursor[d], 1);
        col[pos] = s;
    }
}

// ---------------------------------------------------------------------------
// GEMM (K x 64) + alpha epilogue. Wave handles 4 nodes x 64 cols; thread =
// (node slot, 4 cols). W in LDS read as float4; A read as wave-uniform
// float4 global broadcasts. Writes h as bf16 rows + AS/AD fp32.
// ---------------------------------------------------------------------------
template<int K, int CH>   // CH channels/head; H = 64/CH
__global__ void gemm_alpha(const float* __restrict__ A, const float* __restrict__ W,
                           const float* __restrict__ a_src, const float* __restrict__ a_dst,
                           unsigned short* __restrict__ Hb, float* __restrict__ AS,
                           float* __restrict__ AD, int N) {
    __shared__ float Wl[K * 64];
    const int tid = threadIdx.x;
    for (int i = tid; i < K * 16; i += 256)
        ((float4*)Wl)[i] = ((const float4*)W)[i];
    const int lane = tid & 63, wave = tid >> 6;
    const int l16 = lane & 15, nsub = lane >> 4;
    const int col4 = l16 * 4;
    const int H = 64 / CH;
    const float4 as4 = *(const float4*)&a_src[col4];
    const float4 ad4 = *(const float4*)&a_dst[col4];
    __syncthreads();
    for (int n0 = (blockIdx.x * 4 + wave) * 4; n0 < N; n0 += gridDim.x * 16) {
        int n = n0 + nsub;
        bool ok = n < N;
        const float* Arow = A + (size_t)(ok ? n : n0) * K;
        float4 acc = {0.f, 0.f, 0.f, 0.f};
        #pragma unroll 4
        for (int k4 = 0; k4 < K; k4 += 4) {
            float4 a = *(const float4*)&Arow[k4];
            float4 w0 = *(const float4*)&Wl[(k4 + 0) * 64 + col4];
            float4 w1 = *(const float4*)&Wl[(k4 + 1) * 64 + col4];
            float4 w2 = *(const float4*)&Wl[(k4 + 2) * 64 + col4];
            float4 w3 = *(const float4*)&Wl[(k4 + 3) * 64 + col4];
            acc.x = fmaf(a.x, w0.x, acc.x); acc.y = fmaf(a.x, w0.y, acc.y);
            acc.z = fmaf(a.x, w0.z, acc.z); acc.w = fmaf(a.x, w0.w, acc.w);
            acc.x = fmaf(a.y, w1.x, acc.x); acc.y = fmaf(a.y, w1.y, acc.y);
            acc.z = fmaf(a.y, w1.z, acc.z); acc.w = fmaf(a.y, w1.w, acc.w);
            acc.x = fmaf(a.z, w2.x, acc.x); acc.y = fmaf(a.z, w2.y, acc.y);
            acc.z = fmaf(a.z, w2.z, acc.z); acc.w = fmaf(a.z, w2.w, acc.w);
            acc.x = fmaf(a.w, w3.x, acc.x); acc.y = fmaf(a.w, w3.y, acc.y);
            acc.z = fmaf(a.w, w3.z, acc.z); acc.w = fmaf(a.w, w3.w, acc.w);
        }
        if (ok) {
            union { unsigned short u[4]; uint2 v; } pk;
            pk.u[0] = f2bf(acc.x); pk.u[1] = f2bf(acc.y);
            pk.u[2] = f2bf(acc.z); pk.u[3] = f2bf(acc.w);
            *(uint2*)&Hb[(size_t)n * 64 + col4] = pk.v;
            float vs = acc.x * as4.x + acc.y * as4.y + acc.z * as4.z + acc.w * as4.w;
            float vd = acc.x * ad4.x + acc.y * ad4.y + acc.z * ad4.z + acc.w * ad4.w;
            #pragma unroll
            for (int off = 1; off < CH / 4; off <<= 1) {
                vs += __shfl_xor(vs, off, 64);
                vd += __shfl_xor(vd, off, 64);
            }
            if ((l16 & (CH / 4 - 1)) == 0) {
                int h = col4 / CH;
                AS[(size_t)n * H + h] = vs;
                AD[(size_t)n * H + h] = vd;
            }
        }
    }
}

// ---------------------------------------------------------------------------
// Single-pass softmax aggregation (max-free; e has |e| < ~6, exp safe).
// One wave per dst node; 8 edge slots x 8 lanes; lane covers 8 bf16 channels
// (one uint4 = 16 B gather per edge-slot). Fused bias + ELU / log-softmax.
// ---------------------------------------------------------------------------
template<int H, bool FINAL>
__global__ void aggregate(const int* __restrict__ row_ptr, const int* __restrict__ col,
                          const float* __restrict__ AS, const float* __restrict__ AD,
                          const uint4* __restrict__ Hb, const float* __restrict__ bias,
                          float* __restrict__ OUT, int N) {
    const int CH = 64 / H;
    int lane = threadIdx.x & 63;
    int wid = (blockIdx.x * blockDim.x + threadIdx.x) >> 6;
    int nw = (gridDim.x * blockDim.x) >> 6;
    int slot = lane >> 3, l8 = lane & 7;
    int h = (l8 * 8) / CH;                 // H=8 -> l8 ; H=1 -> 0
    float4 b4a = *(const float4*)&bias[l8 * 8];
    float4 b4b = *(const float4*)&bias[l8 * 8 + 4];
    for (int n = wid; n < N; n += nw) {
        int beg = row_ptr[n], end = row_ptr[n + 1];
        float ad = AD[(size_t)n * H + h];
        float den = 0.0f;
        float acc[8] = {0.f, 0.f, 0.f, 0.f, 0.f, 0.f, 0.f, 0.f};
        for (int base = beg; base < end; base += 64) {
            int cnt = min(64, end - base);
            int myc = (lane < cnt) ? col[base + lane] : 0;
            for (int j = 0; j < cnt; j += 8) {
                int idx = j + slot;
                int s = __shfl(myc, idx, 64);      // safe: invalid lanes hold 0
                float e = AS[(size_t)s * H + h] + ad;
                e = e > 0.0f ? e : NEG_SLOPE * e;
                float p = __expf(e);
                p = (idx < cnt) ? p : 0.0f;
                den += p;
                uint4 hv = Hb[(size_t)s * 8 + l8];
                acc[0] = fmaf(p, bfl(hv.x), acc[0]);
                acc[1] = fmaf(p, bfh(hv.x), acc[1]);
                acc[2] = fmaf(p, bfl(hv.y), acc[2]);
                acc[3] = fmaf(p, bfh(hv.y), acc[3]);
                acc[4] = fmaf(p, bfl(hv.z), acc[4]);
                acc[5] = fmaf(p, bfh(hv.z), acc[5]);
                acc[6] = fmaf(p, bfl(hv.w), acc[6]);
                acc[7] = fmaf(p, bfh(hv.w), acc[7]);
            }
        }
        #pragma unroll
        for (int off = 8; off <= 32; off <<= 1) {
            den += __shfl_xor(den, off, 64);
            #pragma unroll
            for (int i = 0; i < 8; ++i) acc[i] += __shfl_xor(acc[i], off, 64);
        }
        float inv = 1.0f / (den + 1e-16f);
        float v[8];
        v[0] = acc[0] * inv + b4a.x; v[1] = acc[1] * inv + b4a.y;
        v[2] = acc[2] * inv + b4a.z; v[3] = acc[3] * inv + b4a.w;
        v[4] = acc[4] * inv + b4b.x; v[5] = acc[5] * inv + b4b.y;
        v[6] = acc[6] * inv + b4b.z; v[7] = acc[7] * inv + b4b.w;
        if (!FINAL) {
            #pragma unroll
            for (int i = 0; i < 8; ++i) v[i] = v[i] > 0.0f ? v[i] : __expf(v[i]) - 1.0f;
            if (slot == 0) {
                float4 o0 = {v[0], v[1], v[2], v[3]}, o1 = {v[4], v[5], v[6], v[7]};
                *(float4*)&OUT[(size_t)n * 64 + l8 * 8] = o0;
                *(float4*)&OUT[(size_t)n * 64 + l8 * 8 + 4] = o1;
            }
        } else {
            float m = v[0];
            #pragma unroll
            for (int i = 1; i < 8; ++i) m = fmaxf(m, v[i]);
            #pragma unroll
            for (int off = 1; off <= 4; off <<= 1) m = fmaxf(m, __shfl_xor(m, off, 64));
            float ss = 0.0f;
            #pragma unroll
            for (int i = 0; i < 8; ++i) ss += __expf(v[i] - m);
            #pragma unroll
            for (int off = 1; off <= 4; off <<= 1) ss += __shfl_xor(ss, off, 64);
            float lse = m + __logf(ss);
            if (slot == 0) {
                float4 o0 = {v[0] - lse, v[1] - lse, v[2] - lse, v[3] - lse};
                float4 o1 = {v[4] - lse, v[5] - lse, v[6] - lse, v[7] - lse};
                *(float4*)&OUT[(size_t)n * 64 + l8 * 8] = o0;
                *(float4*)&OUT[(size_t)n * 64 + l8 * 8 + 4] = o1;
            }
        }
    }
}

// ---------------------------------------------------------------------------
extern "C" void kernel_launch(void* const* d_in, const int* in_sizes, int n_in,
                              void* d_out, int out_size, void* d_ws, size_t ws_size,
                              hipStream_t stream) {
    const float* x    = (const float*)d_in[0];
    const int*   ei   = (const int*)d_in[1];
    const float* W1   = (const float*)d_in[2];
    const float* as1w = (const float*)d_in[3];
    const float* ad1w = (const float*)d_in[4];
    const float* b1   = (const float*)d_in[5];
    const float* W2   = (const float*)d_in[6];
    const float* as2w = (const float*)d_in[7];
    const float* ad2w = (const float*)d_in[8];
    const float* b2   = (const float*)d_in[9];
    const int N = in_sizes[0] / 128;   // 100000
    const int E = in_sizes[1] / 2;     // 1600000
    const int total = E + N;
    const int NB = (N + SCAN_CHUNK - 1) / SCAN_CHUNK;

    float* ws = (float*)d_ws;
    size_t N64 = (size_t)N * 64, N8 = (size_t)N * 8;
    size_t off = 0;
    float* AGG1 = ws + off; off += N64;            // elu(layer-1 out), fp32
    unsigned short* h1b = (unsigned short*)(ws + off); off += N64 / 2;  // bf16 rows
    unsigned short* h2b = (unsigned short*)(ws + off); off += N64 / 2;
    float* AS1  = ws + off; off += N8;
    float* AD1  = ws + off; off += N8;
    float* AS2  = ws + off; off += N;
    float* AD2  = ws + off; off += N;
    int* row_ptr = (int*)(ws + off);               // N+1
    int* cursor  = row_ptr + (N + 1);              // N
    int* col     = cursor + N;                     // E+N
    int* part    = col + total;                    // 128

    // ---- CSR build (shared by both layers) ----
    hipMemsetAsync(cursor, 0, (size_t)N * sizeof(int), stream);
    histogram<<<4096, 256, 0, stream>>>(ei, E, N, cursor);
    scan_part<<<NB, 256, 0, stream>>>(cursor, N, part);
    scan_tops<<<1, 64, 0, stream>>>(part, NB);
    scan_final<<<NB, 256, 0, stream>>>(cursor, N, total, part, row_ptr, cursor);
    scatter_edges<<<4096, 256, 0, stream>>>(ei, E, N, cursor, col);

    // ---- layer 1 ----
    gemm_alpha<128, 8><<<2048, 256, 0, stream>>>(x, W1, as1w, ad1w, h1b, AS1, AD1, N);
    aggregate<8, false><<<(N + 3) / 4, 256, 0, stream>>>(row_ptr, col, AS1, AD1,
                                                         (const uint4*)h1b, b1, AGG1, N);
    // ---- layer 2 ----
    gemm_alpha<64, 64><<<2048, 256, 0, stream>>>(AGG1, W2, as2w, ad2w, h2b, AS2, AD2, N);
    aggregate<1, true><<<(N + 3) / 4, 256, 0, stream>>>(row_ptr, col, AS2, AD2,
                                                        (const uint4*)h2b, b2, (float*)d_out, N);
}